// Round 2
// baseline (583.161 us; speedup 1.0000x reference)
//
#include <hip/hip_runtime.h>

#define N_NODES  200000
#define N_CHILD  32
#define N_LAYERS 8
#define CHUNK    16384                               // floats per LDS chunk = 64 KB
#define NCHUNK   ((N_NODES + CHUNK - 1) / CHUNK)     // 13
#define NB       256                                 // blocks (1 per CU)
#define NPB      ((N_NODES + NB - 1) / NB)           // 782 nodes per block
#define BT       1024                                // threads per block

// Each block: hold 32 child indices/node in registers, sweep the 800 KB value
// table through LDS in 13 coalesced 64 KB chunks, accumulate via exec-masked
// LDS reads. Turns 6.4M random L2 requests/layer into coalesced float4 streams.
__global__ __launch_bounds__(BT) void layer_kernel(
    const float* __restrict__ vals_in,
    float*       __restrict__ vals_out,
    const int*   __restrict__ child_idx,   // [N_NODES][N_CHILD] this layer
    const int*   __restrict__ fun_ids,     // [N_NODES] this layer
    const float* __restrict__ wptr)
{
    __shared__ float lds[CHUNK];
    const int tid    = threadIdx.x;
    const int node   = blockIdx.x * NPB + tid;
    const bool active = (tid < NPB) && (node < N_NODES);

    // child indices -> registers (8x int4, coalesced across the wave)
    int idx[N_CHILD];
    if (active) {
        const int4* ci = (const int4*)(child_idx + (size_t)node * N_CHILD);
        #pragma unroll
        for (int j = 0; j < N_CHILD / 4; ++j) {
            int4 c = ci[j];
            idx[4*j+0] = c.x; idx[4*j+1] = c.y;
            idx[4*j+2] = c.z; idx[4*j+3] = c.w;
        }
    } else {
        #pragma unroll
        for (int j = 0; j < N_CHILD; ++j) idx[j] = 0;
    }

    float s = 0.0f;
    for (int c = 0; c < NCHUNK; ++c) {
        __syncthreads();   // previous pass done reading LDS
        {
            const int base = c * CHUNK;
            const int n4 = min(CHUNK, N_NODES - base) >> 2;  // both %4==0
            const float4* __restrict__ src = (const float4*)(vals_in + base);
            float4* dst = (float4*)lds;
            for (int i = tid; i < n4; i += BT) dst[i] = src[i];
        }
        __syncthreads();   // chunk staged
        if (active) {
            #pragma unroll
            for (int j = 0; j < N_CHILD; ++j) {
                int id = idx[j];
                if ((id >> 14) == c)           // CHUNK = 2^14
                    s += lds[id & (CHUNK - 1)];
            }
        }
    }

    if (active) {
        float x = wptr[0] * s;
        int fid = fun_ids[node];
        float y;
        if (fid == 0)      y = tanhf(x);
        else if (fid == 1) y = 1.0f / (1.0f + __expf(-x));  // safe at +-inf
        else if (fid == 2) y = fmaxf(x, 0.0f);
        else               y = x;
        vals_out[node] = y;
    }
}

extern "C" void kernel_launch(void* const* d_in, const int* in_sizes, int n_in,
                              void* d_out, int out_size, void* d_ws, size_t ws_size,
                              hipStream_t stream) {
    const float* X         = (const float*)d_in[0];
    const float* w         = (const float*)d_in[1];
    const int*   child_idx = (const int*)d_in[2];
    const int*   fun_ids   = (const int*)d_in[3];
    float*       out       = (float*)d_out;
    float*       bufA      = (float*)d_ws;   // 800 KB ping buffer

    const float* cur = X;
    for (int l = 0; l < N_LAYERS; ++l) {
        // even layers -> bufA, odd layers -> d_out; layer 7 (last) -> d_out
        float* nxt = (l & 1) ? out : bufA;
        layer_kernel<<<NB, BT, 0, stream>>>(
            cur, nxt,
            child_idx + (size_t)l * N_NODES * N_CHILD,
            fun_ids   + (size_t)l * N_NODES,
            w);
        cur = nxt;
    }
}